// Round 7
// baseline (3240.914 us; speedup 1.0000x reference)
//
#include <hip/hip_runtime.h>

// ---------------------------------------------------------------------------
// NER LSTM (B=256,S=128,E=256,H=512,O=32) — one persistent kernel.
// 256 wgs x 256 threads, 1 block/CU. 8 batch groups x 32 col-group wgs
// (g=blockIdx&7). Recurrent weights in VGPRs as f16 MFMA B-frags.
// R14 vs R7..R13: sync micro-variants exhausted (R7 counter barrier is the
// local optimum; R10/R12/R13 all slower). Structural change instead:
// TWO-STREAM INTERLEAVE. Each group's 32 independent batch rows split into
// streams A/B of 16 rows sharing the same wgs and weight registers. Slots
// alternate A(k),B(k),A(k+1)...; each stream has its OWN R7 counter barrier
// (verbatim primitive, separate cache lines). A stream's wait executes after
// the other stream's full compute slot, so the barrier round-trip hides
// under real work instead of being fully exposed. Per-slot compute = half
// (M-tiles 2->1); column/wave structure unchanged (no VGPR growth).
// LDS: per-stream h0s/h1s/xes; shared fcwb (streams run same t), gbuf, lbuf,
// w0d. Transport = R7 sc1/MALL agent stores. Keeps R9's conflict-free
// stageFCW/gatherXE remap idea (per-stream gather).
// ---------------------------------------------------------------------------

#define BN 256
#define SN 128
#define EN 256
#define HN 512
#define ON 32
#define RG 32          // batch rows per group
#define RS 16          // rows per stream
#define NCG 32         // col-group wgs per group
#define NTHREADS 256
#define XSTR 264       // xe stage row stride (f16): 256 + 8 pad
#define HSTR 520       // h  stage row stride (f16): 512 + 8 pad
#define FSTR 520       // fcw stage row stride (f16): 512 + 8 pad
#define GSTR 68        // gbuf row stride (floats): 64 + 4 pad
#define POLL_GUARD (1 << 20)
#define SLB 128        // slots ints per group: [0..31] init flags,
                       // [64] ctrA (own line), [96] ctrB (own line)

typedef _Float16 f16;
typedef _Float16 f16x8 __attribute__((ext_vector_type(8)));
typedef _Float16 f16x4 __attribute__((ext_vector_type(4)));
typedef _Float16 f16x2 __attribute__((ext_vector_type(2)));
typedef float f32x4 __attribute__((ext_vector_type(4)));
typedef unsigned u32x4 __attribute__((ext_vector_type(4)));

__device__ __forceinline__ f32x4 MFMA16(f16x8 a, f16x8 b, f32x4 c) {
  return __builtin_amdgcn_mfma_f32_16x16x32_f16(a, b, c, 0, 0, 0);
}

__device__ __forceinline__ float sigf(float x) { return 1.0f / (1.0f + __expf(-x)); }

// Load B-fragment slice of W [4H x K] (row-major) for column `col`:
// lane holds W[col][kt*32 + quad*8 + j], j=0..7.
template<int NKT>
__device__ __forceinline__ void loadW(const float* __restrict__ Wb, int K, int col, int quad,
                                      f16x8* dst) {
  #pragma unroll
  for (int kt = 0; kt < NKT; ++kt) {
    const float* p = Wb + (size_t)col * K + kt * 32 + quad * 8;
    f32x4 a = *(const f32x4*)p;
    f32x4 b = *(const f32x4*)(p + 4);
    f16x8 h;
    h[0] = (f16)a[0]; h[1] = (f16)a[1]; h[2] = (f16)a[2]; h[3] = (f16)a[3];
    h[4] = (f16)b[0]; h[5] = (f16)b[1]; h[6] = (f16)b[2]; h[7] = (f16)b[3];
    dst[kt] = h;
  }
}

// Issue 4 batched dwordx4 sc1 loads for one [RS x HN] f16 tile (16KB).
__device__ __forceinline__ void issue4(u32x4* v, const char* __restrict__ src, int tid) {
  const char* base = src + tid * 16;
  #pragma unroll
  for (int j = 0; j < 4; ++j)
    asm volatile("global_load_dwordx4 %0, %1, off sc1" : "=v"(v[j]) : "v"(base + j * 4096));
}
// Scatter the 4 loaded vectors into padded LDS (call after the waitcnt).
__device__ __forceinline__ void write4(f16* dst, const u32x4* v, int tid) {
  #pragma unroll
  for (int j = 0; j < 4; ++j) {
    int u = j * 256 + tid, rr = u >> 6, cc = u & 63;
    *(u32x4*)&dst[rr * HSTR + cc * 8] = v[j];
  }
}

// Single-M-tile matmul: acc += stage(rows 0..15) x Wr.
template<int NKT>
__device__ __forceinline__ void matmul1(f32x4& acc, const f16* stage, int stride,
                                        const f16x8* Wr, int l16, int quad) {
  #pragma unroll
  for (int kt = 0; kt < NKT; ++kt) {
    f16x8 a = *(const f16x8*)&stage[l16 * stride + kt * 32 + quad * 8];
    acc = MFMA16(a, Wr[kt], acc);
  }
}

// R7-verbatim counter barrier, parameterized by stream counter offset.
__device__ __forceinline__ void arriveS(int* slots, int g, int soff, int tid) {
  __syncthreads();
  if (tid == 0) {
    asm volatile("s_waitcnt vmcnt(0)" ::: "memory");
    int one = 1;
    int* p = &slots[g * SLB + soff];
    asm volatile("global_atomic_add %0, %1, off" :: "v"(p), "v"(one) : "memory");
  }
}
__device__ __forceinline__ void waitS(int* slots, int g, int soff, int target, int* esc) {
  if (!*esc) {
    const int* p = &slots[g * SLB + soff];
    int gd = 0;
    for (;;) {
      int v = __hip_atomic_load(p, __ATOMIC_RELAXED, __HIP_MEMORY_SCOPE_AGENT);
      if (v >= target) break;
      if (++gd > POLL_GUARD) { *esc = 1; break; }
      __builtin_amdgcn_s_sleep(1);
    }
  }
  asm volatile("" ::: "memory");
}

// Gather one time-step of embeddings for one stream's 16 rows -> xs (f16).
// r=tid&15, sub=tid>>4 (16 subs x 16 floats each).
__device__ __forceinline__ void gatherXE(f16* xs, const int* __restrict__ xTok,
                                         const float* __restrict__ emb, int g, int s, int k,
                                         int tid) {
  int r = tid & 15, sub = tid >> 4;
  int tok = xTok[(g * RG + s * RS + r) * SN + k];
  const float* er = emb + (size_t)tok * EN + sub * 16;
  f16* dst = &xs[r * XSTR + sub * 16];
  #pragma unroll
  for (int jj = 0; jj < 16; jj += 8) {
    f32x4 a = *(const f32x4*)(er + jj);
    f32x4 b = *(const f32x4*)(er + jj + 4);
    f16x8 hv;
    hv[0] = (f16)a[0]; hv[1] = (f16)a[1]; hv[2] = (f16)a[2]; hv[3] = (f16)a[3];
    hv[4] = (f16)b[0]; hv[5] = (f16)b[1]; hv[6] = (f16)b[2]; hv[7] = (f16)b[3];
    *(f16x8*)(dst + jj) = hv;
  }
}

// Stage fcw[st] ([ON][HN] fp32) -> LDS f16 (shared by both streams: same t).
// Thread t handles f32x4 vectors t+j*256 — coalesced, conflict-free.
__device__ __forceinline__ void stageFCW(f16* fcwb, const float* __restrict__ fcw,
                                         int st, int tid) {
  const float* base = fcw + (size_t)st * ON * HN;
  #pragma unroll
  for (int j = 0; j < 16; ++j) {
    int fo = (tid + j * 256) * 4;
    int col = fo >> 9, k = fo & 511;
    f32x4 a = *(const f32x4*)(base + fo);
    f16x4 hv;
    hv[0] = (f16)a[0]; hv[1] = (f16)a[1]; hv[2] = (f16)a[2]; hv[3] = (f16)a[3];
    *(f16x4*)&fcwb[col * FSTR + k] = hv;
  }
}

// fp32 LSTM pointwise for one cell, one stream (16 rows, threads 0..127):
// row=tid>>3, sub=tid&7, dims cg*16+sub*2..+1. Agent store (R7 transport).
__device__ __forceinline__ void pointwise16(const float* gb, float* cv,
                                            unsigned* __restrict__ hout, int rowbase,
                                            int cg, int tid) {
  int row = tid >> 3, sub = tid & 7;
  const float* gr = gb + row * GSTR + sub * 2;
  union { unsigned u; f16x2 h; } hv;
  #pragma unroll
  for (int j = 0; j < 2; ++j) {
    float vi = gr[j], vf = gr[16 + j], vg = gr[32 + j], vo = gr[48 + j];
    cv[j] = sigf(vf) * cv[j] + sigf(vi) * tanhf(vg);
    hv.h[j] = (f16)(sigf(vo) * tanhf(cv[j]));
  }
  __hip_atomic_store(&hout[(rowbase + row) * 256 + cg * 8 + sub], hv.u,
                     __ATOMIC_RELAXED, __HIP_MEMORY_SCOPE_AGENT);
}

__launch_bounds__(NTHREADS, 1)
__global__ void lstm_all(const int* __restrict__ xTok, const float* __restrict__ emb,
    const float* __restrict__ eWih0, const float* __restrict__ eWhh0,
    const float* __restrict__ ebih0, const float* __restrict__ ebhh0,
    const float* __restrict__ eWih1, const float* __restrict__ eWhh1,
    const float* __restrict__ ebih1, const float* __restrict__ ebhh1,
    const float* __restrict__ dWih0, const float* __restrict__ dWhh0,
    const float* __restrict__ dbih0, const float* __restrict__ dbhh0,
    const float* __restrict__ dWih1, const float* __restrict__ dWhh1,
    const float* __restrict__ dbih1, const float* __restrict__ dbhh1,
    const float* __restrict__ fcw, const float* __restrict__ fcb,
    float* __restrict__ dout, char* __restrict__ h0buf, char* __restrict__ h1buf,
    int* __restrict__ slots)
{
  __shared__ __align__(16) f16 h0s[2 * RS * HSTR];   // per-stream h0 stage
  __shared__ __align__(16) f16 h1s[2 * RS * HSTR];   // per-stream h1 stage
  __shared__ __align__(16) f16 xes[2 * RS * XSTR];   // per-stream xe stage
  __shared__ __align__(16) f16 fcwb[ON * FSTR];      // shared (same t both streams)
  __shared__ float gbuf0[RS * GSTR];                 // shared, slot-transient
  __shared__ float gbuf1[RS * GSTR];
  __shared__ __align__(16) char upool[2176 + 8192];  // lbuf [16][33] | w0d [64][32]
  __shared__ int amaxlds[RG];
  __shared__ int esc;

  float* lbuf = (float*)upool;
  float* w0d  = (float*)(upool + 2176);

  const int tid  = threadIdx.x;
  const int g    = blockIdx.x & 7;
  const int cg   = blockIdx.x >> 3;
  const int w    = tid >> 6;              // wave = gate index 0..3
  const int lane = tid & 63;
  const int quad = lane >> 4;
  const int l16  = lane & 15;
  const int colg = w * HN + cg * 16 + l16;
  int ct[2] = {0, 0};                     // per-stream cumulative counter targets
  if (tid == 0) esc = 0;

  // ---- encoder weights -> register B-fragments (shared by both streams)
  f16x8 Wi0r[8], Wh0r[16], Wi1r[16], Wh1r[16];
  loadW<8>(eWih0, EN, colg, quad, Wi0r);
  loadW<16>(eWhh0, HN, colg, quad, Wh0r);
  loadW<16>(eWih1, HN, colg, quad, Wi1r);
  loadW<16>(eWhh1, HN, colg, quad, Wh1r);
  float bias0 = ebih0[colg] + ebhh0[colg];
  float bias1 = ebih1[colg] + ebhh1[colg];

  // ---- xe(0) pre-gather (both streams); zero h(-1) parity 1; zero cells
  gatherXE(&xes[0],             xTok, emb, g, 0, 0, tid);
  gatherXE(&xes[RS * XSTR],     xTok, emb, g, 1, 0, tid);
  float c0s[2][2] = {{0.f, 0.f}, {0.f, 0.f}};
  float c1s[2][2] = {{0.f, 0.f}, {0.f, 0.f}};
  {
    int urow = tid >> 3;                  // 32 rows x 8 subs
    unsigned idx = (unsigned)(BN * 256 + (g * RG + urow) * 256 + cg * 8 + (tid & 7));
    __hip_atomic_store((unsigned*)h0buf + idx, 0u, __ATOMIC_RELAXED, __HIP_MEMORY_SCOPE_AGENT);
    __hip_atomic_store((unsigned*)h1buf + idx, 0u, __ATOMIC_RELAXED, __HIP_MEMORY_SCOPE_AGENT);
  }
  // ---- INIT barrier (R7-proven): drain, reset BOTH counters, publish flag.
  asm volatile("s_waitcnt vmcnt(0)" ::: "memory");
  __syncthreads();
  if (tid == 0) {
    __hip_atomic_store(&slots[g * SLB + 64], 0, __ATOMIC_RELAXED, __HIP_MEMORY_SCOPE_AGENT);
    __hip_atomic_store(&slots[g * SLB + 96], 0, __ATOMIC_RELAXED, __HIP_MEMORY_SCOPE_AGENT);
    asm volatile("s_waitcnt vmcnt(0)" ::: "memory");
    __hip_atomic_store(&slots[g * SLB + cg], 1, __ATOMIC_RELAXED, __HIP_MEMORY_SCOPE_AGENT);
  }
  if (!esc) {
    int idx = tid & 31;
    int gd = 0;
    for (;;) {
      int v = __hip_atomic_load(&slots[g * SLB + idx], __ATOMIC_RELAXED,
                                __HIP_MEMORY_SCOPE_AGENT);
      if (__all(v >= 1)) break;
      if (++gd > POLL_GUARD) { esc = 1; break; }
      __builtin_amdgcn_s_sleep(1);
    }
  }
  __syncthreads();

  // ================= encoder: slot(s,k) = cell0@k + cell1@(k-1) for stream s
  for (int k = 0; k <= SN; ++k) {
    #pragma unroll
    for (int s = 0; s < 2; ++s) {
      const int soff = 64 + s * 32;
      f16* h0ss = &h0s[s * RS * HSTR];
      f16* h1ss = &h1s[s * RS * HSTR];
      f16* xss  = &xes[s * RS * XSTR];
      const size_t rbyte = (size_t)(g * RG + s * RS) * HN * 2;

      waitS(slots, g, soff, ct[s], &esc);   // prev round of THIS stream

      u32x4 v0[4], v1[4];
      issue4(v0, h0buf + (size_t)((k - 1) & 1) * BN * HN * 2 + rbyte, tid);
      if (k >= 1)
        issue4(v1, h1buf + (size_t)(k & 1) * BN * HN * 2 + rbyte, tid);

      f32x4 a0, a1;
      if (k < SN) {   // xe part of cell0 overlaps the stage loads
        a0[0] = bias0; a0[1] = bias0; a0[2] = bias0; a0[3] = bias0;
        matmul1<8>(a0, xss, XSTR, Wi0r, l16, quad);
      }
      if (k >= 1) asm volatile("s_waitcnt vmcnt(4)" ::: "memory");
      else        asm volatile("s_waitcnt vmcnt(0)" ::: "memory");
      write4(h0ss, v0, tid);
      __syncthreads();
      if (k < SN) matmul1<16>(a0, h0ss, HSTR, Wh0r, l16, quad);
      if (k >= 1) {
        a1[0] = bias1; a1[1] = bias1; a1[2] = bias1; a1[3] = bias1;
        matmul1<16>(a1, h0ss, HSTR, Wi1r, l16, quad);
        asm volatile("s_waitcnt vmcnt(0)" ::: "memory");
        write4(h1ss, v1, tid);
        __syncthreads();
        matmul1<16>(a1, h1ss, HSTR, Wh1r, l16, quad);
      }

      #pragma unroll
      for (int i = 0; i < 4; ++i) {
        int rr = (quad * 4 + i) * GSTR + w * 16 + l16;
        if (k < SN) gbuf0[rr] = a0[i];
        if (k >= 1) gbuf1[rr] = a1[i];
      }
      __syncthreads();
      if (tid < 128) {
        if (k < SN)
          pointwise16(gbuf0, c0s[s], (unsigned*)(h0buf + (size_t)(k & 1) * BN * HN * 2),
                      g * RG + s * RS, cg, tid);
        if (k >= 1)
          pointwise16(gbuf1, c1s[s], (unsigned*)(h1buf + (size_t)((k - 1) & 1) * BN * HN * 2),
                      g * RG + s * RS, cg, tid);
      }
      arriveS(slots, g, soff, tid);
      ct[s] += NCG;
      if (k < SN - 1) gatherXE(xss, xTok, emb, g, s, k + 1, tid);  // in the gap
      __syncthreads();
    }
  }

  // ================= decoder setup
  loadW<16>(dWhh0, HN, colg, quad, Wh0r);
  loadW<16>(dWih1, HN, colg, quad, Wi1r);
  loadW<16>(dWhh1, HN, colg, quad, Wh1r);
  bias0 = dbih0[colg] + dbhh0[colg];
  bias1 = dbih1[colg] + dbhh1[colg];
  {   // dec_Wih0 slice [64 owned cols][32 inputs] -> LDS
    int cl = tid >> 2, i0 = (tid & 3) * 8;
    int gcol = (cl >> 4) * HN + cg * 16 + (cl & 15);
    const float* p = dWih0 + (size_t)gcol * ON + i0;
    #pragma unroll
    for (int j = 0; j < 8; ++j) w0d[cl * 32 + i0 + j] = p[j];
  }
  if (tid < RG) amaxlds[tid] = 0;   // xin(0) = one-hot(0), both streams
  __syncthreads();
  // h0s_s holds h0@127 (staged at k=SN); h1buf parity1 = h1@127; c-states carry.

  // ================= decoder: per t: I1(A), I1(B), I2(A), I2(B)
  for (int t = 0; t <= SN; ++t) {
    #pragma unroll
    for (int s = 0; s < 2; ++s) {   // ---- I1 slots
      const int soff = 64 + s * 32;
      f16* h0ss = &h0s[s * RS * HSTR];
      f16* h1ss = &h1s[s * RS * HSTR];
      const size_t rbyte = (size_t)(g * RG + s * RS) * HN * 2;

      waitS(slots, g, soff, ct[s], &esc);

      u32x4 v0[4];
      issue4(v0, h1buf + (size_t)((t - 1) & 1) * BN * HN * 2 + rbyte, tid);
      f32x4 a0;
      if (t < SN) {   // Whh0 part (h0ss ready) overlaps the h1 stage
        a0[0] = 0.f; a0[1] = 0.f; a0[2] = 0.f; a0[3] = 0.f;
        matmul1<16>(a0, h0ss, HSTR, Wh0r, l16, quad);
      }
      float fb = 0.f;
      if (t >= 1 && w < 2) fb = fcb[(t - 1) * ON + w * 16 + l16];
      asm volatile("s_waitcnt vmcnt(0)" ::: "memory");
      write4(h1ss, v0, tid);
      __syncthreads();

      if (t >= 1) {
        if (w < 2) {   // FC: 2 waves, N-tile = w, M=16, K=512
          f32x4 afc = {0.f, 0.f, 0.f, 0.f};
          #pragma unroll
          for (int kt = 0; kt < 16; ++kt) {
            f16x8 bf = *(const f16x8*)&fcwb[(w * 16 + l16) * FSTR + kt * 32 + quad * 8];
            f16x8 av = *(const f16x8*)&h1ss[l16 * HSTR + kt * 32 + quad * 8];
            afc = MFMA16(av, bf, afc);
          }
          #pragma unroll
          for (int i = 0; i < 4; ++i)
            lbuf[(quad * 4 + i) * 33 + w * 16 + l16] = afc[i] + fb;
        }
        __syncthreads();
        if (tid < 128) {   // softmax + argmax: 8 threads per row, 16 rows
          int st = t - 1;
          int row = tid >> 3, s8 = tid & 7, cbase = s8 * 4;
          float vv[4];
          #pragma unroll
          for (int j = 0; j < 4; ++j) vv[j] = lbuf[row * 33 + cbase + j];
          float mx = vv[0]; int bi = cbase;
          #pragma unroll
          for (int j = 1; j < 4; ++j)
            if (vv[j] > mx) { mx = vv[j]; bi = cbase + j; }
          #pragma unroll
          for (int m = 1; m < 8; m <<= 1) {
            float om = __shfl_xor(mx, m);
            int   ob = __shfl_xor(bi, m);
            if (om > mx || (om == mx && ob < bi)) { mx = om; bi = ob; }
          }
          float e[4], ss = 0.f;
          #pragma unroll
          for (int j = 0; j < 4; ++j) { e[j] = __expf(vv[j] - mx); ss += e[j]; }
          #pragma unroll
          for (int m = 1; m < 8; m <<= 1) ss += __shfl_xor(ss, m);
          if (s8 == 0) amaxlds[s * RS + row] = bi;
          if (cg == 0) {
            float inv = 1.0f / ss;
            float* op = dout + ((size_t)(g * RG + s * RS + row) * SN + st) * ON + cbase;
            #pragma unroll
            for (int j = 0; j < 4; ++j) op[j] = e[j] * inv;
          }
        }
        __syncthreads();
      }

      if (t < SN) {   // bias + one-hot gather, exchange, pointwise cell0
        #pragma unroll
        for (int i = 0; i < 4; ++i)
          a0[i] += bias0 + w0d[(w * 16 + l16) * 32 + amaxlds[s * RS + quad * 4 + i]];
        #pragma unroll
        for (int i = 0; i < 4; ++i)
          gbuf0[(quad * 4 + i) * GSTR + w * 16 + l16] = a0[i];
        __syncthreads();
        if (tid < 128)
          pointwise16(gbuf0, c0s[s], (unsigned*)(h0buf + (size_t)(t & 1) * BN * HN * 2),
                      g * RG + s * RS, cg, tid);
      }
      arriveS(slots, g, soff, tid);
      ct[s] += NCG;
    }

    if (t < SN) {
      #pragma unroll
      for (int s = 0; s < 2; ++s) {   // ---- I2 slots
        const int soff = 64 + s * 32;
        f16* h0ss = &h0s[s * RS * HSTR];
        f16* h1ss = &h1s[s * RS * HSTR];
        const size_t rbyte = (size_t)(g * RG + s * RS) * HN * 2;

        waitS(slots, g, soff, ct[s], &esc);

        u32x4 v2[4];
        issue4(v2, h0buf + (size_t)(t & 1) * BN * HN * 2 + rbyte, tid);
        f32x4 a1;
        a1[0] = bias1; a1[1] = bias1; a1[2] = bias1; a1[3] = bias1;
        matmul1<16>(a1, h1ss, HSTR, Wh1r, l16, quad);   // h1@(t-1), overlaps stage
        asm volatile("s_waitcnt vmcnt(0)" ::: "memory");
        write4(h0ss, v2, tid);
        __syncthreads();
        matmul1<16>(a1, h0ss, HSTR, Wi1r, l16, quad);
        #pragma unroll
        for (int i = 0; i < 4; ++i)
          gbuf0[(quad * 4 + i) * GSTR + w * 16 + l16] = a1[i];
        __syncthreads();
        if (tid < 128)
          pointwise16(gbuf0, c1s[s], (unsigned*)(h1buf + (size_t)(t & 1) * BN * HN * 2),
                      g * RG + s * RS, cg, tid);
        arriveS(slots, g, soff, tid);
        ct[s] += NCG;
        if (s == 0) stageFCW(fcwb, fcw, t, tid);   // fcw[t] for both I1(t+1) slots
        __syncthreads();
      }
    }
  }
}

extern "C" void kernel_launch(void* const* d_in, const int* in_sizes, int n_in,
                              void* d_out, int out_size, void* d_ws, size_t ws_size,
                              hipStream_t stream) {
  (void)in_sizes; (void)n_in; (void)out_size; (void)ws_size;
  const int*   xTok  = (const int*)d_in[0];
  const float* emb   = (const float*)d_in[1];
  const float* eWih0 = (const float*)d_in[2];
  const float* eWhh0 = (const float*)d_in[3];
  const float* ebih0 = (const float*)d_in[4];
  const float* ebhh0 = (const float*)d_in[5];
  const float* eWih1 = (const float*)d_in[6];
  const float* eWhh1 = (const float*)d_in[7];
  const float* ebih1 = (const float*)d_in[8];
  const float* ebhh1 = (const float*)d_in[9];
  const float* dWih0 = (const float*)d_in[10];
  const float* dWhh0 = (const float*)d_in[11];
  const float* dbih0 = (const float*)d_in[12];
  const float* dbhh0 = (const float*)d_in[13];
  const float* dWih1 = (const float*)d_in[14];
  const float* dWhh1 = (const float*)d_in[15];
  const float* dbih1 = (const float*)d_in[16];
  const float* dbhh1 = (const float*)d_in[17];
  const float* fcw   = (const float*)d_in[18];
  const float* fcb   = (const float*)d_in[19];

  // ws layout: h0buf [2][256][512] f16 (512KB) | h1buf (512KB) |
  // slots [8][128] int (4KB; per group: [0..31] init flags, [64] ctrA,
  // [96] ctrB — all agent/MALL)
  char* h0buf = (char*)d_ws;
  char* h1buf = (char*)d_ws + (size_t)2 * BN * HN * 2;
  int*  slots = (int*)((char*)d_ws + (size_t)4 * BN * HN * 2);

  hipLaunchKernelGGL(lstm_all, dim3(256), dim3(NTHREADS), 0, stream,
                     xTok, emb, eWih0, eWhh0, ebih0, ebhh0, eWih1, eWhh1, ebih1, ebhh1,
                     dWih0, dWhh0, dbih0, dbhh0, dWih1, dWhh1, dbih1, dbhh1,
                     fcw, fcb, (float*)d_out, h0buf, h1buf, slots);
}

// Round 8
// 2855.808 us; speedup vs baseline: 1.1349x; 1.1349x over previous
//
#include <hip/hip_runtime.h>

// ---------------------------------------------------------------------------
// NER LSTM (B=256,S=128,E=256,H=512,O=32) — one persistent kernel.
// 256 wgs x 256 threads, 1 block/CU. 8 batch groups (32 rows) x 32 col-group
// wgs (g=blockIdx&7). Recurrent weights in VGPRs as f16 MFMA B-frags.
// R15 vs R14/R13/R7: R14 proved round-count must not grow (772 rounds lost
// 833us). R7's single-counter barrier remains best; its one never-isolated
// leg is the 32 serializing RMW atomic_adds on ONE MALL line (~60-100ns each
// of exclusive ownership => the 32nd add, which gates detection, lands 2-3us
// after the first — the unexplained 3us of the 6.2us round). R15 shards the
// arrive across 8 counter lines:
//  - arrive: wg cg adds to line (cg&7) — 4 adds/line/round, worst-case
//    serialization 4x~100ns instead of 32x. Same fire-and-forget
//    global_atomic_add, same per-wave vmcnt drain + __syncthreads ordering.
//  - wait: every lane polls line (lane&7) with relaxed agent LOADS
//    (read-only, no ownership churn; 8 lanes mirror each line) until
//    __all(v >= 4*rnd). Monotone >=, overshoot-safe — R7 semantics.
//  - init: tid0 zeroes its line (4 redundant zero-writers/line, harmless),
//    drains, publishes init flag — all resets visible before any add.
// Transport verbatim R7 (sc1/MALL agent stores). Keeps R9's conflict-free
// stageFCW / gatherXE remaps (bit-identical, proven R12/R13/R14).
// ---------------------------------------------------------------------------

#define BN 256
#define SN 128
#define EN 256
#define HN 512
#define ON 32
#define RG 32          // batch rows per group
#define NCG 32         // col-group wgs per group
#define NTHREADS 256
#define XSTR 264       // xe stage row stride (f16): 256 + 8 pad
#define HSTR 520       // h  stage row stride (f16): 512 + 8 pad
#define FSTR 520       // fcw stage row stride (f16): 512 + 8 pad
#define GSTR 68        // gbuf row stride (floats): 64 + 4 pad
#define POLL_GUARD (1 << 20)
#define SLB 512        // slots ints per group: [0..31] init flags,
                       // counter line i at [64 + i*32], i=0..7 (128B apart)

typedef _Float16 f16;
typedef _Float16 f16x8 __attribute__((ext_vector_type(8)));
typedef _Float16 f16x4 __attribute__((ext_vector_type(4)));
typedef _Float16 f16x2 __attribute__((ext_vector_type(2)));
typedef float f32x4 __attribute__((ext_vector_type(4)));
typedef unsigned u32x4 __attribute__((ext_vector_type(4)));

__device__ __forceinline__ f32x4 MFMA16(f16x8 a, f16x8 b, f32x4 c) {
  return __builtin_amdgcn_mfma_f32_16x16x32_f16(a, b, c, 0, 0, 0);
}

__device__ __forceinline__ float sigf(float x) { return 1.0f / (1.0f + __expf(-x)); }

// Load B-fragment slice of W [4H x K] (row-major) for column `col`:
// lane holds W[col][kt*32 + quad*8 + j], j=0..7.
template<int NKT>
__device__ __forceinline__ void loadW(const float* __restrict__ Wb, int K, int col, int quad,
                                      f16x8* dst) {
  #pragma unroll
  for (int kt = 0; kt < NKT; ++kt) {
    const float* p = Wb + (size_t)col * K + kt * 32 + quad * 8;
    f32x4 a = *(const f32x4*)p;
    f32x4 b = *(const f32x4*)(p + 4);
    f16x8 h;
    h[0] = (f16)a[0]; h[1] = (f16)a[1]; h[2] = (f16)a[2]; h[3] = (f16)a[3];
    h[4] = (f16)b[0]; h[5] = (f16)b[1]; h[6] = (f16)b[2]; h[7] = (f16)b[3];
    dst[kt] = h;
  }
}

// Issue 8 batched dwordx4 sc1 stage loads for one [RG x HN] f16 tile (32KB).
__device__ __forceinline__ void issue8(u32x4* v, const char* __restrict__ src, int tid) {
  const char* base = src + tid * 16;
  #pragma unroll
  for (int j = 0; j < 8; ++j)
    asm volatile("global_load_dwordx4 %0, %1, off sc1" : "=v"(v[j]) : "v"(base + j * 4096));
}
// Scatter the 8 loaded vectors into padded LDS (call after the waitcnt).
__device__ __forceinline__ void write8(f16* dst, const u32x4* v, int tid) {
  #pragma unroll
  for (int j = 0; j < 8; ++j) {
    int u = j * 256 + tid, rr = u >> 6, cc = u & 63;
    *(u32x4*)&dst[rr * HSTR + cc * 8] = v[j];
  }
}

// acc[mt] += stage(rows mt*16..) x Wr   (A[m=lane&15][k=quad*8+j] layout)
template<int NKT>
__device__ __forceinline__ void matmulAcc(f32x4* acc, const f16* stage, int stride,
                                          const f16x8* Wr, int l16, int quad) {
  #pragma unroll
  for (int mt = 0; mt < 2; ++mt) {
    #pragma unroll
    for (int kt = 0; kt < NKT; ++kt) {
      f16x8 a = *(const f16x8*)&stage[(mt * 16 + l16) * stride + kt * 32 + quad * 8];
      acc[mt] = MFMA16(a, Wr[kt], acc[mt]);
    }
  }
}

// Sharded arrive: per-wave vmcnt drain (h stores MALL-visible) + barrier,
// then tid0 fires ONE fire-and-forget atomic add on line (cg&7). 4 adds per
// line per round — the serialized-RMW tail is 4 deep, not 32.
__device__ __forceinline__ void arrive_ctr8(int* slots, int g, int cg, int tid) {
  asm volatile("s_waitcnt vmcnt(0)" ::: "memory");
  __syncthreads();
  if (tid == 0) {
    int one = 1;
    int* p = &slots[g * SLB + 64 + (cg & 7) * 32];
    asm volatile("global_atomic_add %0, %1, off" :: "v"(p), "v"(one) : "memory");
  }
}

// Sharded wait: every lane polls line (lane&7) (8 lanes mirror each line,
// read-only agent loads) until ALL lines reach 4*rnd. Escape guard in LDS.
__device__ __forceinline__ void wait_ctr8(int* slots, int g, int tid, int target, int* esc) {
  if (!*esc) {
    const int* p = &slots[g * SLB + 64 + (tid & 7) * 32];
    int gd = 0;
    for (;;) {
      int v = __hip_atomic_load(p, __ATOMIC_RELAXED, __HIP_MEMORY_SCOPE_AGENT);
      if (__all(v >= target)) break;
      if (++gd > POLL_GUARD) { *esc = 1; break; }
      __builtin_amdgcn_s_sleep(1);
    }
  }
  asm volatile("" ::: "memory");
}

// Gather one time-step of embeddings for the group's 32 rows -> xes (f16).
// r=tid&31, sub=tid>>5: octet lanes hit distinct bank groups (conflict-free).
__device__ __forceinline__ void gatherXE(f16* xes, const int* __restrict__ xTok,
                                         const float* __restrict__ emb, int g, int k, int tid) {
  int r = tid & 31, sub = tid >> 5;
  int tok = xTok[(g * RG + r) * SN + k];
  const float* er = emb + (size_t)tok * EN + sub * 32;
  f16* dst = &xes[r * XSTR + sub * 32];
  #pragma unroll
  for (int jj = 0; jj < 32; jj += 8) {
    f32x4 a = *(const f32x4*)(er + jj);
    f32x4 b = *(const f32x4*)(er + jj + 4);
    f16x8 hv;
    hv[0] = (f16)a[0]; hv[1] = (f16)a[1]; hv[2] = (f16)a[2]; hv[3] = (f16)a[3];
    hv[4] = (f16)b[0]; hv[5] = (f16)b[1]; hv[6] = (f16)b[2]; hv[7] = (f16)b[3];
    *(f16x8*)(dst + jj) = hv;
  }
}

// Stage fcw[st] ([ON][HN] fp32) -> LDS f16. Thread t handles f32x4 vectors
// t + j*256: coalesced 1KB/wave global reads, conflict-free ds_write_b64.
// Same RTE cvt per element as before => bit-identical logits.
__device__ __forceinline__ void stageFCW(f16* fcwb, const float* __restrict__ fcw,
                                         int st, int tid) {
  const float* base = fcw + (size_t)st * ON * HN;
  #pragma unroll
  for (int j = 0; j < 16; ++j) {
    int fo = (tid + j * 256) * 4;        // float offset 0..16380
    int col = fo >> 9, k = fo & 511;
    f32x4 a = *(const f32x4*)(base + fo);
    f16x4 hv;
    hv[0] = (f16)a[0]; hv[1] = (f16)a[1]; hv[2] = (f16)a[2]; hv[3] = (f16)a[3];
    *(f16x4*)&fcwb[col * FSTR + k] = hv;
  }
}

// fp32 LSTM pointwise for one cell from a gate buffer + packed f16x2 agent
// atomic store (MALL, R7-proven transport).
__device__ __forceinline__ void pointwise_store(const float* gb, int row, int d0, float* cv,
                                                unsigned* __restrict__ hout, int g, int cg,
                                                int sub) {
  const float* gr = gb + row * GSTR + d0;
  union { unsigned u; f16x2 h; } hv;
  #pragma unroll
  for (int j = 0; j < 2; ++j) {
    float vi = gr[j], vf = gr[16 + j], vg = gr[32 + j], vo = gr[48 + j];
    cv[j] = sigf(vf) * cv[j] + sigf(vi) * tanhf(vg);
    hv.h[j] = (f16)(sigf(vo) * tanhf(cv[j]));
  }
  __hip_atomic_store(&hout[(g * RG + row) * 256 + cg * 8 + sub], hv.u,
                     __ATOMIC_RELAXED, __HIP_MEMORY_SCOPE_AGENT);
}

__launch_bounds__(NTHREADS, 1)
__global__ void lstm_all(const int* __restrict__ xTok, const float* __restrict__ emb,
    const float* __restrict__ eWih0, const float* __restrict__ eWhh0,
    const float* __restrict__ ebih0, const float* __restrict__ ebhh0,
    const float* __restrict__ eWih1, const float* __restrict__ eWhh1,
    const float* __restrict__ ebih1, const float* __restrict__ ebhh1,
    const float* __restrict__ dWih0, const float* __restrict__ dWhh0,
    const float* __restrict__ dbih0, const float* __restrict__ dbhh0,
    const float* __restrict__ dWih1, const float* __restrict__ dWhh1,
    const float* __restrict__ dbih1, const float* __restrict__ dbhh1,
    const float* __restrict__ fcw, const float* __restrict__ fcb,
    float* __restrict__ dout, char* __restrict__ h0buf, char* __restrict__ h1buf,
    int* __restrict__ slots)
{
  __shared__ __align__(16) char upool[RG * XSTR * 2];  // enc: xe stage | dec: lbuf + w0d
  __shared__ __align__(16) f16 h0s[RG * HSTR];
  __shared__ __align__(16) f16 h1s[RG * HSTR];
  __shared__ __align__(16) f16 fcwb[ON * FSTR];
  __shared__ float gbuf0[RG * GSTR];
  __shared__ float gbuf1[RG * GSTR];
  __shared__ int amaxlds[RG];
  __shared__ int esc;

  f16*   xes  = (f16*)upool;
  float* lbuf = (float*)upool;            // [RG][33] logits (decoder only)
  float* w0d  = (float*)(upool + 4352);   // [64][32] dec_Wih0 slice (decoder only)

  const int tid  = threadIdx.x;
  const int g    = blockIdx.x & 7;        // batch group
  const int cg   = blockIdx.x >> 3;       // col-group within group, 0..31
  const int w    = tid >> 6;              // wave = gate index 0..3
  const int lane = tid & 63;
  const int quad = lane >> 4;
  const int l16  = lane & 15;
  const int colg = w * HN + cg * 16 + l16;  // global gate column (2048-space)
  const int urow = tid >> 3;              // pointwise: row 0..31
  const int ud0  = (tid & 7) * 2;         // pointwise: dim pair base
  int ctarget = 0;                        // cumulative per-line target (+4/round)
  if (tid == 0) esc = 0;

  // ---- encoder weights -> register B-fragments
  f16x8 Wi0r[8], Wh0r[16], Wi1r[16], Wh1r[16];
  loadW<8>(eWih0, EN, colg, quad, Wi0r);
  loadW<16>(eWhh0, HN, colg, quad, Wh0r);
  loadW<16>(eWih1, HN, colg, quad, Wi1r);
  loadW<16>(eWhh1, HN, colg, quad, Wh1r);
  float bias0 = ebih0[colg] + ebhh0[colg];
  float bias1 = ebih1[colg] + ebhh1[colg];

  // ---- xe(0) pre-gather; zero h(-1) (parity 1); zero cell state
  gatherXE(xes, xTok, emb, g, 0, tid);
  float c0[2] = {0.f, 0.f}, c1[2] = {0.f, 0.f};
  {
    unsigned idx = (unsigned)(BN * 256 + (g * RG + urow) * 256 + cg * 8 + (tid & 7));
    __hip_atomic_store((unsigned*)h0buf + idx, 0u, __ATOMIC_RELAXED, __HIP_MEMORY_SCOPE_AGENT);
    __hip_atomic_store((unsigned*)h1buf + idx, 0u, __ATOMIC_RELAXED, __HIP_MEMORY_SCOPE_AGENT);
  }
  // ---- INIT barrier (R7-proven flag protocol). Per-wave vmcnt drain +
  // barrier => h-zero stores retired. tid0 then: zero counter line (cg&7)
  // (4 redundant zero-writers per line, all-zero, harmless), drain, THEN
  // publish init flag. Any wg seeing all 32 init flags sees all resets.
  asm volatile("s_waitcnt vmcnt(0)" ::: "memory");
  __syncthreads();
  if (tid == 0) {
    __hip_atomic_store(&slots[g * SLB + 64 + (cg & 7) * 32], 0, __ATOMIC_RELAXED,
                       __HIP_MEMORY_SCOPE_AGENT);
    asm volatile("s_waitcnt vmcnt(0)" ::: "memory");
    __hip_atomic_store(&slots[g * SLB + cg], 1, __ATOMIC_RELAXED, __HIP_MEMORY_SCOPE_AGENT);
  }
  if (!esc) {
    int idx = tid & 31;
    int gd = 0;
    for (;;) {
      int v = __hip_atomic_load(&slots[g * SLB + idx], __ATOMIC_RELAXED,
                                __HIP_MEMORY_SCOPE_AGENT);
      if (__all(v >= 1)) break;
      if (++gd > POLL_GUARD) { esc = 1; break; }
      __builtin_amdgcn_s_sleep(1);
    }
  }
  __syncthreads();

  // ================= encoder: interval k does cell0@k + cell1@(k-1)
  for (int k = 0; k <= SN; ++k) {
    u32x4 v0[8], v1[8];
    issue8(v0, h0buf + (size_t)((k - 1) & 1) * BN * HN * 2 + (size_t)(g * RG) * HN * 2, tid);
    if (k >= 1)
      issue8(v1, h1buf + (size_t)(k & 1) * BN * HN * 2 + (size_t)(g * RG) * HN * 2, tid);

    f32x4 acc0[2], acc1[2];
    if (k < SN) {   // xe part of cell0 overlaps the stage loads
      f32x4 b0; b0[0] = bias0; b0[1] = bias0; b0[2] = bias0; b0[3] = bias0;
      acc0[0] = b0; acc0[1] = b0;
      matmulAcc<8>(acc0, xes, XSTR, Wi0r, l16, quad);
    }
    if (k >= 1) asm volatile("s_waitcnt vmcnt(8)" ::: "memory");  // h0 batch retired
    else        asm volatile("s_waitcnt vmcnt(0)" ::: "memory");
    write8(h0s, v0, tid);
    __syncthreads();
    if (k < SN) matmulAcc<16>(acc0, h0s, HSTR, Wh0r, l16, quad);   // h1 still in flight
    if (k >= 1) {
      f32x4 b1; b1[0] = bias1; b1[1] = bias1; b1[2] = bias1; b1[3] = bias1;
      acc1[0] = b1; acc1[1] = b1;
      matmulAcc<16>(acc1, h0s, HSTR, Wi1r, l16, quad);
      asm volatile("s_waitcnt vmcnt(0)" ::: "memory");
      write8(h1s, v1, tid);
      __syncthreads();
      matmulAcc<16>(acc1, h1s, HSTR, Wh1r, l16, quad);
    }

    // merged exchange: both cells, one sync, one pointwise pass
    #pragma unroll
    for (int mt = 0; mt < 2; ++mt) {
      #pragma unroll
      for (int i = 0; i < 4; ++i) {
        int rr = (mt * 16 + quad * 4 + i) * GSTR + w * 16 + l16;
        if (k < SN) gbuf0[rr] = acc0[mt][i];
        if (k >= 1) gbuf1[rr] = acc1[mt][i];
      }
    }
    __syncthreads();
    if (k < SN)
      pointwise_store(gbuf0, urow, ud0, c0,
                      (unsigned*)(h0buf + (size_t)(k & 1) * BN * HN * 2), g, cg, tid & 7);
    if (k >= 1)
      pointwise_store(gbuf1, urow, ud0, c1,
                      (unsigned*)(h1buf + (size_t)((k - 1) & 1) * BN * HN * 2), g, cg, tid & 7);

    ctarget += 4;
    arrive_ctr8(slots, g, cg, tid);
    if (k < SN - 1) gatherXE(xes, xTok, emb, g, k + 1, tid);   // hidden in the gap
    __syncthreads();   // gather-complete guard
    wait_ctr8(slots, g, tid, ctarget, &esc);
  }

  // ================= decoder setup: swap weight regs to decoder weights
  loadW<16>(dWhh0, HN, colg, quad, Wh0r);
  loadW<16>(dWih1, HN, colg, quad, Wi1r);
  loadW<16>(dWhh1, HN, colg, quad, Wh1r);
  bias0 = dbih0[colg] + dbhh0[colg];
  bias1 = dbih1[colg] + dbhh1[colg];
  {   // dec_Wih0 slice [64 owned cols][32 inputs] -> LDS (one-hot gather table)
    int cl = tid >> 2, i0 = (tid & 3) * 8;
    int gcol = (cl >> 4) * HN + cg * 16 + (cl & 15);
    const float* p = dWih0 + (size_t)gcol * ON + i0;
    #pragma unroll
    for (int j = 0; j < 8; ++j) w0d[cl * 32 + i0 + j] = p[j];
  }
  if (tid < RG) amaxlds[tid] = 0;   // xin(0) = one-hot(0)
  // h0s holds h0@127 (staged at k=128); h1buf parity1 = h1@127; c0,c1 carry.

  // ================= decoder: I1 = [fc+softmax+amax@(t-1)] + cell0@t ; I2 = cell1@t
  for (int t = 0; t <= SN; ++t) {
    u32x4 v0[8];
    issue8(v0, h1buf + (size_t)((t - 1) & 1) * BN * HN * 2 + (size_t)(g * RG) * HN * 2, tid);
    float fb = 0.f;
    if (t >= 1) fb = fcb[(t - 1) * ON + ((w >> 1) * 16 + l16)];   // early, off-chain-ish

    f32x4 acc0[2];
    if (t < SN) {   // Whh0 part of cell0 (h0s ready) overlaps the h1 stage
      acc0[0] = f32x4{0.f, 0.f, 0.f, 0.f}; acc0[1] = acc0[0];
      matmulAcc<16>(acc0, h0s, HSTR, Wh0r, l16, quad);
    }
    asm volatile("s_waitcnt vmcnt(0)" ::: "memory");
    write8(h1s, v0, tid);
    __syncthreads();

    if (t >= 1) {
      int fmt = w & 1, fnt = w >> 1;
      int colo = fnt * 16 + l16;
      f32x4 afc = {0.f, 0.f, 0.f, 0.f};
      #pragma unroll
      for (int kt = 0; kt < 16; ++kt) {   // B-frags from LDS (prefetched in I2 gap)
        f16x8 bf = *(const f16x8*)&fcwb[colo * FSTR + kt * 32 + quad * 8];
        f16x8 av = *(const f16x8*)&h1s[(fmt * 16 + l16) * HSTR + kt * 32 + quad * 8];
        afc = MFMA16(av, bf, afc);
      }
      #pragma unroll
      for (int i = 0; i < 4; ++i)
        lbuf[(fmt * 16 + quad * 4 + i) * 33 + colo] = afc[i] + fb;
      __syncthreads();
      {   // parallel softmax + argmax: 8 threads per row, shfl_xor reductions
        int st = t - 1;
        int row = tid >> 3, s = tid & 7, cbase = s * 4;
        float vv[4];
        #pragma unroll
        for (int j = 0; j < 4; ++j) vv[j] = lbuf[row * 33 + cbase + j];
        float mx = vv[0]; int bi = cbase;
        #pragma unroll
        for (int j = 1; j < 4; ++j)
          if (vv[j] > mx) { mx = vv[j]; bi = cbase + j; }
        #pragma unroll
        for (int m = 1; m < 8; m <<= 1) {
          float om = __shfl_xor(mx, m);
          int   ob = __shfl_xor(bi, m);
          if (om > mx || (om == mx && ob < bi)) { mx = om; bi = ob; }
        }
        float e[4], ss = 0.f;
        #pragma unroll
        for (int j = 0; j < 4; ++j) { e[j] = __expf(vv[j] - mx); ss += e[j]; }
        #pragma unroll
        for (int m = 1; m < 8; m <<= 1) ss += __shfl_xor(ss, m);
        if (s == 0) amaxlds[row] = bi;
        if (cg == 0) {
          float inv = 1.0f / ss;
          float* op = dout + ((size_t)(g * RG + row) * SN + st) * ON + cbase;
          #pragma unroll
          for (int j = 0; j < 4; ++j) op[j] = e[j] * inv;
        }
      }
      __syncthreads();
    }

    if (t < SN) {   // add bias + one-hot gather(dec_Wih0, amax), then exchange
      #pragma unroll
      for (int mt = 0; mt < 2; ++mt) {
        #pragma unroll
        for (int i = 0; i < 4; ++i) {
          int row = mt * 16 + quad * 4 + i;
          acc0[mt][i] += bias0 + w0d[(w * 16 + l16) * 32 + amaxlds[row]];
        }
      }
      #pragma unroll
      for (int mt = 0; mt < 2; ++mt) {
        #pragma unroll
        for (int i = 0; i < 4; ++i)
          gbuf0[(mt * 16 + quad * 4 + i) * GSTR + w * 16 + l16] = acc0[mt][i];
      }
      __syncthreads();
      pointwise_store(gbuf0, urow, ud0, c0,
                      (unsigned*)(h0buf + (size_t)(t & 1) * BN * HN * 2), g, cg, tid & 7);
    }
    ctarget += 4;
    arrive_ctr8(slots, g, cg, tid);
    wait_ctr8(slots, g, tid, ctarget, &esc);

    if (t < SN) {   // I2: cell1@t : h0@t@Wih1^T + h1@(t-1)@Whh1^T + b
      u32x4 v2[8];
      issue8(v2, h0buf + (size_t)(t & 1) * BN * HN * 2 + (size_t)(g * RG) * HN * 2, tid);
      f32x4 acc1[2];
      f32x4 b1; b1[0] = bias1; b1[1] = bias1; b1[2] = bias1; b1[3] = bias1;
      acc1[0] = b1; acc1[1] = b1;
      matmulAcc<16>(acc1, h1s, HSTR, Wh1r, l16, quad);   // h1@(t-1), overlaps stage
      asm volatile("s_waitcnt vmcnt(0)" ::: "memory");
      write8(h0s, v2, tid);
      __syncthreads();
      matmulAcc<16>(acc1, h0s, HSTR, Wi1r, l16, quad);
      #pragma unroll
      for (int mt = 0; mt < 2; ++mt) {
        #pragma unroll
        for (int i = 0; i < 4; ++i)
          gbuf0[(mt * 16 + quad * 4 + i) * GSTR + w * 16 + l16] = acc1[mt][i];
      }
      __syncthreads();
      pointwise_store(gbuf0, urow, ud0, c1,
                      (unsigned*)(h1buf + (size_t)(t & 1) * BN * HN * 2), g, cg, tid & 7);
      ctarget += 4;
      arrive_ctr8(slots, g, cg, tid);
      stageFCW(fcwb, fcw, t, tid);   // fcw[st=t] for next I1 — hidden in the gap
      __syncthreads();               // staging-complete guard
      wait_ctr8(slots, g, tid, ctarget, &esc);
    }
  }
}

extern "C" void kernel_launch(void* const* d_in, const int* in_sizes, int n_in,
                              void* d_out, int out_size, void* d_ws, size_t ws_size,
                              hipStream_t stream) {
  (void)in_sizes; (void)n_in; (void)out_size; (void)ws_size;
  const int*   xTok  = (const int*)d_in[0];
  const float* emb   = (const float*)d_in[1];
  const float* eWih0 = (const float*)d_in[2];
  const float* eWhh0 = (const float*)d_in[3];
  const float* ebih0 = (const float*)d_in[4];
  const float* ebhh0 = (const float*)d_in[5];
  const float* eWih1 = (const float*)d_in[6];
  const float* eWhh1 = (const float*)d_in[7];
  const float* ebih1 = (const float*)d_in[8];
  const float* ebhh1 = (const float*)d_in[9];
  const float* dWih0 = (const float*)d_in[10];
  const float* dWhh0 = (const float*)d_in[11];
  const float* dbih0 = (const float*)d_in[12];
  const float* dbhh0 = (const float*)d_in[13];
  const float* dWih1 = (const float*)d_in[14];
  const float* dWhh1 = (const float*)d_in[15];
  const float* dbih1 = (const float*)d_in[16];
  const float* dbhh1 = (const float*)d_in[17];
  const float* fcw   = (const float*)d_in[18];
  const float* fcb   = (const float*)d_in[19];

  // ws layout: h0buf [2][256][512] f16 (512KB) | h1buf (512KB) |
  // slots [8][512] int (16KB; per group: [0..31] init flags, counter line i
  // at [64+i*32], i=0..7 — all agent/MALL)
  char* h0buf = (char*)d_ws;
  char* h1buf = (char*)d_ws + (size_t)2 * BN * HN * 2;
  int*  slots = (int*)((char*)d_ws + (size_t)4 * BN * HN * 2);

  hipLaunchKernelGGL(lstm_all, dim3(256), dim3(NTHREADS), 0, stream,
                     xTok, emb, eWih0, eWhh0, ebih0, ebhh0, eWih1, eWhh1, ebih1, ebhh1,
                     dWih0, dWhh0, dbih0, dbhh0, dWih1, dWhh1, dbih1, dbhh1,
                     fcw, fcb, (float*)d_out, h0buf, h1buf, slots);
}